// Round 12
// baseline (401.796 us; speedup 1.0000x reference)
//
#include <hip/hip_runtime.h>
#include <hip/hip_bf16.h>

// LocalBlock: tpose+LN1 -> qkv GEMM -> multi-dilate attn(+xn) -> proj GEMM(+x, bf16 y)
//            -> LN2 -> fc1+gelu -> fc2(+y, transposed f32 out)
// gemmF: barrier-free wave-independent GEMM. 32-row A-strip resident in LDS (staged once),
//   B streamed from L2-resident 1KB bricks into a depth-4 register ring, per-wave
//   private LDS patch for coalesced stores. 784 blocks (~1 generation), 3 blocks/CU.

#define B_   8
#define C_   384
#define W_   56
#define HW_  3136
#define N_   25088
#define HID_ 1536
#define C3_  1152

typedef __attribute__((ext_vector_type(8))) short short8v;
typedef __attribute__((ext_vector_type(4))) float f32x4;
typedef __attribute__((ext_vector_type(4))) unsigned short ushort4v;

__device__ __forceinline__ float bf2f(unsigned short u) {
  union { float f; unsigned u; } c; c.u = ((unsigned)u) << 16; return c.f;
}
__device__ __forceinline__ unsigned short f2bf(float f) {
  unsigned u = __float_as_uint(f);
  u = (u + 0x7FFFu + ((u >> 16) & 1u)) >> 16;
  return (unsigned short)u;
}
__device__ __forceinline__ float gelu_fast(float x) {
  const float z = 1.5957691216057308f * (x + 0.044715f * x * x * x);
  return x / (1.f + __expf(-z));
}

#define GLL(gsrc, ldst) __builtin_amdgcn_global_load_lds( \
    (const __attribute__((address_space(1))) void*)(gsrc), \
    (__attribute__((address_space(3))) void*)(ldst), 16, 0, 0)

// ---------------- weight fp32 -> bf16 MFMA bricks ----------------
// brick: 16 n x 32 k = 512 ushort, lane-linear: lane = (n&15) + (((k>>3)&3)<<4), elem = k&7
// addr = ((n>>4)*(K>>5) + (k>>5))*512 + lane*8 + elem   [verified rounds 4/5]
__device__ __forceinline__ void brick_one(const float* src, unsigned short* dst,
                                          int idx, int K) {
  const int n = idx / K, k = idx - n * K;
  const int lane = (n & 15) + (((k >> 3) & 3) << 4);
  dst[(size_t)((n >> 4) * (K >> 5) + (k >> 5)) * 512 + lane * 8 + (k & 7)] = f2bf(src[idx]);
}
__global__ void repack_w(const float* __restrict__ qw, const float* __restrict__ pw,
                         const float* __restrict__ f1, const float* __restrict__ f2,
                         unsigned short* __restrict__ o) {
  int i = blockIdx.x * 256 + threadIdx.x;
  if (i < 442368)        brick_one(qw, o, i, 384);
  else if (i < 589824)   brick_one(pw, o + 442368, i - 442368, 384);
  else if (i < 1179648)  brick_one(f1, o + 589824, i - 589824, 384);
  else if (i < 1769472)  brick_one(f2, o + 1179648, i - 1179648, 1536);
}

// ---------------- fused transpose + LN1: x[B,C,HW] -> xpb[N,C] bf16, xn[N,C] bf16 ---------
__global__ __launch_bounds__(256)
void tpose_ln(const float* __restrict__ x, unsigned short* __restrict__ xpb,
              unsigned short* __restrict__ xnb,
              const float* __restrict__ gam, const float* __restrict__ bet) {
  __shared__ float ft[64][385];
  __shared__ float mstat[64], rstat[64];
  const int tid = threadIdx.x;
  const int nb0 = blockIdx.x * 64;
  const int bb = nb0 / HW_, hw0 = nb0 - bb * HW_;
  const float* xb = x + (size_t)bb * C_ * HW_ + hw0;
#pragma unroll
  for (int p = 0; p < 24; ++p) {
    const int c = p * 16 + (tid >> 4);
    f32x4 v = *(const f32x4*)&xb[(size_t)c * HW_ + (tid & 15) * 4];
#pragma unroll
    for (int j = 0; j < 4; ++j) ft[(tid & 15) * 4 + j][c] = v[j];
  }
  __syncthreads();
  const int l16 = tid & 15, g16 = tid >> 4;
#pragma unroll
  for (int rr = 0; rr < 4; ++rr) {
    const int row = g16 * 4 + rr;
    float s = 0.f, ss = 0.f;
#pragma unroll
    for (int k2 = 0; k2 < 24; ++k2) { float v = ft[row][l16 + k2 * 16]; s += v; ss += v * v; }
    s += __shfl_xor(s, 8); ss += __shfl_xor(ss, 8);
    s += __shfl_xor(s, 4); ss += __shfl_xor(ss, 4);
    s += __shfl_xor(s, 2); ss += __shfl_xor(ss, 2);
    s += __shfl_xor(s, 1); ss += __shfl_xor(ss, 1);
    if (l16 == 0) {
      const float mean = s * (1.f / 384.f);
      const float var = ss * (1.f / 384.f) - mean * mean;
      mstat[row] = mean; rstat[row] = rsqrtf(var + 1e-5f);
    }
  }
  __syncthreads();
  const int row = tid >> 2, part = tid & 3;
  const float mean = mstat[row], rstd = rstat[row];
  unsigned short* xpr = xpb + (size_t)(nb0 + row) * C_ + part * 96;
  unsigned short* xr = xnb + (size_t)(nb0 + row) * C_ + part * 96;
#pragma unroll
  for (int q = 0; q < 12; ++q) {
    short8v oraw, oln;
#pragma unroll
    for (int e = 0; e < 8; ++e) {
      const int c = part * 96 + q * 8 + e;
      const float v = ft[row][c];
      oraw[e] = (short)f2bf(v);
      oln[e] = (short)f2bf((v - mean) * rstd * gam[c] + bet[c]);
    }
    *(short8v*)&xpr[q * 8] = oraw;
    *(short8v*)&xr[q * 8] = oln;
  }
}

// ---------------- row LayerNorm bf16 -> bf16 (LN2) ----------------
__global__ __launch_bounds__(256)
void ln_rows(const unsigned short* __restrict__ in, unsigned short* __restrict__ outb,
             const float* __restrict__ g, const float* __restrict__ bb) {
  const int row = blockIdx.x * 4 + (threadIdx.x >> 6);
  const int l = threadIdx.x & 63;
  float v[8]; float s = 0.f, ss = 0.f;
  if (l < 48) {
    short8v r = *(const short8v*)&in[(size_t)row * C_ + l * 8];
#pragma unroll
    for (int e = 0; e < 8; ++e) { v[e] = bf2f((unsigned short)r[e]); s += v[e]; ss += v[e] * v[e]; }
  }
#pragma unroll
  for (int off = 32; off; off >>= 1) { s += __shfl_xor(s, off); ss += __shfl_xor(ss, off); }
  const float mean = s * (1.f / 384.f);
  const float var = ss * (1.f / 384.f) - mean * mean;
  const float rstd = rsqrtf(var + 1e-5f);
  if (l < 48) {
    short8v o;
#pragma unroll
    for (int e = 0; e < 8; ++e) {
      const int c = l * 8 + e;
      o[e] = (short)f2bf((v[e] - mean) * rstd * g[c] + bb[c]);
    }
    *(short8v*)&outb[(size_t)row * C_ + l * 8] = o;
  }
}

// ---------------- gemmF: out[M,NOUT] = A[M,K] @ W[NOUT,K]^T (bricked W) ----------------
// block = 256 thr (4 waves), m-strip 32 rows. A staged once (swizzled), then NO barriers:
// wave w sweeps n-groups g = w, w+4, ... (48 cols each, acc[2][3]); B via depth-4 reg ring.
// MODE 0: bf16 (qkv)  MODE 1: bf16 = resid+v+bias (proj)  MODE 2: bf16 gelu(v+bias) (fc1)
// MODE 3: f32 d_out[B,C,HW] = resid+v+bias transposed (fc2, K=1536 in 4 chunks)
template <int MODE, int NOUT, int K>
__global__ __launch_bounds__(256, 3)
void gemmF(const unsigned short* __restrict__ A, const unsigned short* __restrict__ Wb,
           const float* __restrict__ bias, const unsigned short* __restrict__ resid,
           void* __restrict__ outp) {
  constexpr int KBR = K / 32;          // bricks per n-brick-row
  constexpr int GPW = NOUT / 192;      // n-groups per wave
  __shared__ unsigned short sm[(MODE == 3) ? 24576 : 18432];
  const int tid = threadIdx.x, l = tid & 63, wv = tid >> 6;
  const int fr = l & 15, gh = l >> 4, g4 = gh << 2;

  const int bid = blockIdx.x;                     // 784 = 8*98, bijective XCD swizzle
  const int wg = (bid & 7) * 98 + (bid >> 3);
  const int m0 = wg * 32;

  auto stageA = [&](int ck) {
#pragma unroll
    for (int r = 0; r < 6; ++r) {
      const int slot = r * 256 + tid;             // 0..1535
      const int row = slot / 48, s = slot - row * 48;
      GLL(A + (size_t)(m0 + row) * K + ck * 384 + ((s ^ (row & 7)) << 3), &sm[slot * 8]);
    }
  };
  auto ldA = [&](int mt, int kt) -> short8v {
    const int row = mt * 16 + fr;
    return *(const short8v*)&sm[row * 384 + ((((kt << 2) + gh) ^ (fr & 7)) << 3)];
  };
  auto ldB = [&](short8v* dst, int g, int kb) {
#pragma unroll
    for (int nt = 0; nt < 3; ++nt)
      dst[nt] = *(const short8v*)(Wb + (size_t)((g * 3 + nt) * KBR + kb) * 512 + l * 8);
  };

  short8v b[4][3];

  if constexpr (MODE != 3) {
    stageA(0);
    asm volatile("s_waitcnt vmcnt(0)" ::: "memory");
    __syncthreads();
    ldB(b[0], wv, 0); ldB(b[1], wv, 1); ldB(b[2], wv, 2); ldB(b[3], wv, 3);

    for (int gi = 0; gi < GPW; ++gi) {
      const int g = wv + 4 * gi;
      f32x4 acc[2][3] = {};
#pragma unroll
      for (int kb4 = 0; kb4 < 3; ++kb4) {
#pragma unroll
        for (int j = 0; j < 4; ++j) {
          const int kt = kb4 * 4 + j;
          const short8v a0 = ldA(0, kt);
          const short8v a1 = ldA(1, kt);
#pragma unroll
          for (int nt = 0; nt < 3; ++nt) {
            acc[0][nt] = __builtin_amdgcn_mfma_f32_16x16x32_bf16(b[j][nt], a0, acc[0][nt], 0, 0, 0);
            acc[1][nt] = __builtin_amdgcn_mfma_f32_16x16x32_bf16(b[j][nt], a1, acc[1][nt], 0, 0, 0);
          }
          if (kt + 4 < 12) ldB(b[j], g, kt + 4);
          else if (gi + 1 < GPW) ldB(b[j], g + 4, kt - 8);
        }
      }
      // ---- per-wave epilogue via private LDS patch (no cross-wave sync) ----
      unsigned short* patch = &sm[12288 + wv * 1536];   // [32 m][48 n] bf16
#pragma unroll
      for (int mt = 0; mt < 2; ++mt)
#pragma unroll
        for (int nt = 0; nt < 3; ++nt) {
          ushort4v pk;
#pragma unroll
          for (int j = 0; j < 4; ++j) pk[j] = f2bf(acc[mt][nt][j]);
          *(ushort4v*)&patch[(mt * 16 + fr) * 48 + nt * 16 + g4] = pk;
        }
      asm volatile("s_waitcnt lgkmcnt(0)" ::: "memory");
      __builtin_amdgcn_sched_barrier(0);
      unsigned short* op = (unsigned short*)outp;
      const int nb = g * 48;
#pragma unroll
      for (int it = 0; it < 3; ++it) {
        const int slot = it * 64 + l;               // 0..191 : row = slot/6, grp = slot%6
        const int row = slot / 6, grp = slot - row * 6;
        short8v v = *(const short8v*)&patch[row * 48 + grp * 8];
        const int n = nb + grp * 8;
        if constexpr (MODE == 2) {
          const f32x4 b0 = *(const f32x4*)&bias[n];
          const f32x4 b1 = *(const f32x4*)&bias[n + 4];
#pragma unroll
          for (int e = 0; e < 8; ++e)
            v[e] = (short)f2bf(gelu_fast(bf2f((unsigned short)v[e]) + (e < 4 ? b0[e] : b1[e - 4])));
        } else if constexpr (MODE == 1) {
          const f32x4 b0 = *(const f32x4*)&bias[n];
          const f32x4 b1 = *(const f32x4*)&bias[n + 4];
          const short8v r8 = *(const short8v*)&resid[(size_t)(m0 + row) * C_ + n];
#pragma unroll
          for (int e = 0; e < 8; ++e)
            v[e] = (short)f2bf(bf2f((unsigned short)v[e]) + (e < 4 ? b0[e] : b1[e - 4])
                               + bf2f((unsigned short)r8[e]));
        }
        *(short8v*)&op[(size_t)(m0 + row) * NOUT + n] = v;
      }
    }
  } else {
    // fc2: K = 1536 in 4 chunks, acc persists (all indices static via unroll)
    f32x4 acc2[2][2][3] = {};
    for (int ck = 0; ck < 4; ++ck) {
      if (ck) __syncthreads();
      stageA(ck);
      asm volatile("s_waitcnt vmcnt(0)" ::: "memory");
      __syncthreads();
      const int kb0 = ck * 12;
      ldB(b[0], wv, kb0); ldB(b[1], wv, kb0 + 1); ldB(b[2], wv, kb0 + 2); ldB(b[3], wv, kb0 + 3);
#pragma unroll
      for (int gi = 0; gi < 2; ++gi) {
        const int g = wv + 4 * gi;
#pragma unroll
        for (int kb4 = 0; kb4 < 3; ++kb4) {
#pragma unroll
          for (int j = 0; j < 4; ++j) {
            const int kt = kb4 * 4 + j;
            const short8v a0 = ldA(0, kt);
            const short8v a1 = ldA(1, kt);
#pragma unroll
            for (int nt = 0; nt < 3; ++nt) {
              acc2[gi][0][nt] = __builtin_amdgcn_mfma_f32_16x16x32_bf16(b[j][nt], a0, acc2[gi][0][nt], 0, 0, 0);
              acc2[gi][1][nt] = __builtin_amdgcn_mfma_f32_16x16x32_bf16(b[j][nt], a1, acc2[gi][1][nt], 0, 0, 0);
            }
            if (kt + 4 < 12) ldB(b[j], g, kb0 + kt + 4);
            else if (gi == 0) ldB(b[j], g + 4, kb0 + kt - 8);
          }
        }
      }
    }
    // epilogue: f32 transposed store to d_out[B,C,HW]; per-wave patch [48 c][32 m] f32
    float* out = (float*)outp;
    const int bb = m0 / HW_, hw0 = m0 - bb * HW_;
#pragma unroll
    for (int gi = 0; gi < 2; ++gi) {
      const int g = wv + 4 * gi;
      float* patch = (float*)&sm[12288 + wv * 3072];   // 1536 floats
#pragma unroll
      for (int mt = 0; mt < 2; ++mt)
#pragma unroll
        for (int nt = 0; nt < 3; ++nt) {
          const int c0 = nt * 16 + g4;
          const int cg0 = g * 48 + c0;
          const f32x4 bi = *(const f32x4*)&bias[cg0];
          const int m = mt * 16 + fr;
          const ushort4v r4 = *(const ushort4v*)&resid[(size_t)(m0 + m) * C_ + cg0];
          f32x4 v = acc2[gi][mt][nt];
#pragma unroll
          for (int j = 0; j < 4; ++j)
            patch[(c0 + j) * 32 + m] = v[j] + bi[j] + bf2f((unsigned short)r4[j]);
        }
      asm volatile("s_waitcnt lgkmcnt(0)" ::: "memory");
      __builtin_amdgcn_sched_barrier(0);
#pragma unroll
      for (int it = 0; it < 6; ++it) {
        const int slot = it * 64 + l;                  // 0..383 : cl = slot>>3, mq = slot&7
        const int cl = slot >> 3, mq = slot & 7;
        f32x4 v = *(const f32x4*)&patch[cl * 32 + mq * 4];
        const int cgl = g * 48 + cl;
        *(f32x4*)&out[((size_t)bb * C_ + cgl) * HW_ + hw0 + mq * 4] = v;
      }
      asm volatile("s_waitcnt lgkmcnt(0)" ::: "memory");
    }
  }
}

// ---------------- multi-dilate local attention (+xn) ----------------
__global__ __launch_bounds__(256)
void attn_kernel(const unsigned short* __restrict__ qkv,
                 const unsigned short* __restrict__ xn,
                 unsigned short* __restrict__ aout) {
  const int gid = blockIdx.x * 256 + threadIdx.x;
  const int n = gid / 12;
  const int r = gid - n * 12;
  const int dil = (r >> 2) + 1;
  const int b = n / HW_;
  const int hw = n - b * HW_;
  const int h = hw / W_;
  const int w = hw - h * W_;

  const size_t base = (size_t)n * C3_ + (size_t)r * 32;
  float q[32];
  {
    const short8v* vp = (const short8v*)(qkv + base);
#pragma unroll
    for (int c8 = 0; c8 < 4; ++c8) {
      short8v v = vp[c8];
#pragma unroll
      for (int e = 0; e < 8; ++e) q[c8 * 8 + e] = bf2f((unsigned short)v[e]);
    }
  }

  float logit[9];
#pragma unroll
  for (int ti = 0; ti < 3; ++ti)
#pragma unroll
    for (int tj = 0; tj < 3; ++tj) {
      const int t = ti * 3 + tj;
      const int hn = h + (ti - 1) * dil, wn = w + (tj - 1) * dil;
      if ((unsigned)hn < 56u && (unsigned)wn < 56u) {
        const int nb = n + (ti - 1) * dil * W_ + (tj - 1) * dil;
        const short8v* kp = (const short8v*)(qkv + (size_t)nb * C3_ + C_ + (size_t)r * 32);
        float dot = 0.f;
#pragma unroll
        for (int c8 = 0; c8 < 4; ++c8) {
          short8v v = kp[c8];
#pragma unroll
          for (int e = 0; e < 8; ++e) dot += q[c8 * 8 + e] * bf2f((unsigned short)v[e]);
        }
        logit[t] = dot * 0.17677669529663688f;
      } else {
        logit[t] = 0.f;  // zero-padded taps participate with logit 0
      }
    }

  float mx = logit[0];
#pragma unroll
  for (int t = 1; t < 9; ++t) mx = fmaxf(mx, logit[t]);
  float wgt[9]; float se = 0.f;
#pragma unroll
  for (int t = 0; t < 9; ++t) { wgt[t] = __expf(logit[t] - mx); se += wgt[t]; }
  const float inv = 1.f / se;

  float acc[32];
#pragma unroll
  for (int c = 0; c < 32; ++c) acc[c] = 0.f;
#pragma unroll
  for (int ti = 0; ti < 3; ++ti)
#pragma unroll
    for (int tj = 0; tj < 3; ++tj) {
      const int t = ti * 3 + tj;
      const int hn = h + (ti - 1) * dil, wn = w + (tj - 1) * dil;
      if ((unsigned)hn < 56u && (unsigned)wn < 56u) {
        const int nb = n + (ti - 1) * dil * W_ + (tj - 1) * dil;
        const short8v* vp = (const short8v*)(qkv + (size_t)nb * C3_ + 2 * C_ + (size_t)r * 32);
        const float wt = wgt[t];
#pragma unroll
        for (int c8 = 0; c8 < 4; ++c8) {
          short8v v = vp[c8];
#pragma unroll
          for (int e = 0; e < 8; ++e) acc[c8 * 8 + e] += wt * bf2f((unsigned short)v[e]);
        }
      }
    }

  const size_t obase = (size_t)n * C_ + (size_t)r * 32;
  const short8v* xv = (const short8v*)(xn + obase);
  short8v ov[4];
#pragma unroll
  for (int c8 = 0; c8 < 4; ++c8) {
    short8v v = xv[c8];
#pragma unroll
    for (int e = 0; e < 8; ++e)
      ov[c8][e] = (short)f2bf(acc[c8 * 8 + e] * inv + bf2f((unsigned short)v[e]));
  }
  short8v* op = (short8v*)(aout + obase);
#pragma unroll
  for (int c8 = 0; c8 < 4; ++c8) op[c8] = ov[c8];
}

extern "C" void kernel_launch(void* const* d_in, const int* in_sizes, int n_in,
                              void* d_out, int out_size, void* d_ws, size_t ws_size,
                              hipStream_t stream) {
  const float* x = (const float*)d_in[0];
  const float* qkv_w = (const float*)d_in[1];
  const float* proj_w = (const float*)d_in[2];
  const float* proj_b = (const float*)d_in[3];
  const float* n1_g = (const float*)d_in[4];
  const float* n1_b = (const float*)d_in[5];
  const float* n2_g = (const float*)d_in[6];
  const float* n2_b = (const float*)d_in[7];
  const float* fc1_w = (const float*)d_in[8];
  const float* fc1_b = (const float*)d_in[9];
  const float* fc2_w = (const float*)d_in[10];
  const float* fc2_b = (const float*)d_in[11];

  char* ws = (char*)d_ws;
  unsigned short* xpb = (unsigned short*)ws;                     // [N,C] bf16 (x transposed)
  unsigned short* xn = (unsigned short*)(ws + 19267584);         // [N,C] bf16 (LN1/LN2 out)
  unsigned short* qkvb = (unsigned short*)(ws + 38535168);       // [N,1152] bf16
  unsigned short* abuf = (unsigned short*)(ws + 96337920);       // [N,C] bf16
  unsigned short* y = (unsigned short*)(ws + 115605504);         // [N,C] bf16 residual stream
  unsigned short* hbuf = qkvb;                                   // [N,1536] bf16 (reuse)
  unsigned short* wq = (unsigned short*)(ws + 134873088);        // bricked weights
  unsigned short* wp = wq + 442368;
  unsigned short* wf1 = wp + 147456;
  unsigned short* wf2 = wf1 + 589824;

  repack_w<<<6912, 256, 0, stream>>>(qkv_w, proj_w, fc1_w, fc2_w, wq);
  tpose_ln<<<392, 256, 0, stream>>>(x, xpb, xn, n1_g, n1_b);
  gemmF<0, C3_, C_><<<784, 256, 0, stream>>>(xn, wq, nullptr, nullptr, qkvb);
  attn_kernel<<<1176, 256, 0, stream>>>(qkvb, xn, abuf);
  gemmF<1, C_, C_><<<784, 256, 0, stream>>>(abuf, wp, proj_b, xpb, y);
  ln_rows<<<6272, 256, 0, stream>>>(y, xn, n2_g, n2_b);
  gemmF<2, HID_, C_><<<784, 256, 0, stream>>>(xn, wf1, fc1_b, nullptr, hbuf);
  gemmF<3, C_, HID_><<<784, 256, 0, stream>>>(hbuf, wf2, fc2_b, y, (float*)d_out);
}